// Round 11
// baseline (575.809 us; speedup 1.0000x reference)
//
#include <hip/hip_runtime.h>
#include <hip/hip_fp16.h>
#include <cmath>

// Problem constants
constexpr int B_ = 64, N_ = 50000, L_ = 8, E_ = 100000, U_ = 20000, G_ = 20000, R_ = 64, D_ = 16, C_ = 2;
constexpr int EPL_ = E_ + 3 * U_ + 4096;  // padded edge slots per layer
constexpr int EPLG_ = EPL_ / 4 + 64;      // group slots per layer
constexpr int GPW = 8;                    // groups per wave span (32 edges)
constexpr int GCAP = EPL_ / 4;
constexpr int SW = (GCAP + GPW - 1) / GPW;
constexpr int CNTS = 16;                  // cnt stride: 1 counter per 64B line
constexpr int HISTB4 = (E_ / 4 + 255) / 256;  // hist blocks/layer, 4 edges/thr

// Classic geometry (fallback): full batch, 2 KB rows.
constexpr int BC = 64;
constexpr int F = BC * 2;

// Arena geometry: HALF batch, 1 KB rows -> versioned arena fits 256 MiB ws.
// phys row 0 = zero row; rows 1..G = gene rows; row DST0+li*U+u = layer-li
// output for dst u. ssrc remapped (separate pass) to phys rows valid BEFORE
// layer li -> same-layer reads/writes disjoint. Two passes over batch halves.
constexpr int HBC = 32;
constexpr int FH = HBC * 2;               // 64 float4 chunks/row (1 KB)
constexpr int DST0 = 1 + G_;
constexpr int AROWS = DST0 + L_ * U_;     // 180001 rows = 184.3 MB

__device__ __forceinline__ float tanh_fast(float x) {
  float e = __expf(2.0f * x);
  return 1.0f - 2.0f * __builtin_amdgcn_rcpf(e + 1.0f);
}

// ---------------- CSR build ----------------

// Fused histogram(+rank) + (arena) versioning mark.
// Hist: 4 edges/thread (int4), padded counters (1/64B line) — r10 PMC showed
// 57us from ~80-way same-line atomic serialization + 1 atomic round-trip per
// thread. 4 independent atomics/thread overlap latency; padding kills line
// contention. Blocks x>=HISTB4 (y==0): posarr/wmask/lw0 build.
__global__ __launch_bounds__(256) void hist_mark_k(
    const int* __restrict__ dst_pos, int* __restrict__ cnt,
    int* __restrict__ rank, const int* __restrict__ dst_unique,
    const int* __restrict__ gene_map, int* __restrict__ wmask,
    int* __restrict__ posarr, int* __restrict__ lw0) {
  int li = blockIdx.y;
  int bx = blockIdx.x;
  if (bx < HISTB4) {
    int e4 = (bx * 256 + threadIdx.x) * 4;
    if (e4 < E_) {
      int4 dp = *(const int4*)(dst_pos + (size_t)li * E_ + e4);
      int r0 = atomicAdd(&cnt[((size_t)li * U_ + dp.x) * CNTS], 1);
      int r1 = atomicAdd(&cnt[((size_t)li * U_ + dp.y) * CNTS], 1);
      int r2 = atomicAdd(&cnt[((size_t)li * U_ + dp.z) * CNTS], 1);
      int r3 = atomicAdd(&cnt[((size_t)li * U_ + dp.w) * CNTS], 1);
      *(int4*)(rank + (size_t)li * E_ + e4) = make_int4(r0, r1, r2, r3);
    }
  } else if (li == 0) {
    int t = (bx - HISTB4) * 256 + threadIdx.x;
    if (t < L_ * U_) {
      int lj = t / U_, u = t % U_;
      int n = dst_unique[t];
      posarr[lj * N_ + n] = u;
      atomicOr(&wmask[n], 1 << lj);
    } else {
      int g = t - L_ * U_;
      if (g < G_) lw0[gene_map[g]] = 1 + g;
    }
  }
}

// Scan (8 blocks): counts padded to mult of 4, empty u -> 4 slots.
__global__ __launch_bounds__(1024) void scan_kernel(
    const int* __restrict__ cnt, int* __restrict__ offs) {
  __shared__ int sums[1024];
  int li = blockIdx.x, t = threadIdx.x;
  int base = t * 20;
  int v[20];
  int s = 0;
#pragma unroll
  for (int i = 0; i < 20; ++i) {
    int idx = base + i;
    int c = (idx < U_) ? cnt[((size_t)li * U_ + idx) * CNTS] : -1;
    int pc = (c < 0) ? 0 : ((c == 0) ? 4 : ((c + 3) & ~3));
    v[i] = s;
    s += pc;
  }
  sums[t] = s;
  __syncthreads();
  for (int off = 1; off < 1024; off <<= 1) {
    int o = (t >= off) ? sums[t - off] : 0;
    __syncthreads();
    sums[t] += o;
    __syncthreads();
  }
  int excl = sums[t] - s;
#pragma unroll
  for (int i = 0; i < 20; ++i) {
    int idx = base + i;
    if (idx < U_) offs[li * (U_ + 1) + idx] = excl + v[i];
  }
  if (t == 1023) offs[li * (U_ + 1) + U_] = sums[1023];
}

// Atomic-free scatter, 4 edges/thread: position = offs[u] + precomputed rank.
__global__ __launch_bounds__(256) void scatter_kernel(
    const int* __restrict__ dst_pos, const int* __restrict__ src,
    const int* __restrict__ offs, const int* __restrict__ rank,
    int* __restrict__ ssrc) {
  int e4 = (blockIdx.x * 256 + threadIdx.x) * 4;
  int li = blockIdx.y;
  if (e4 >= E_) return;
  int4 dp = *(const int4*)(dst_pos + (size_t)li * E_ + e4);
  int4 rk = *(const int4*)(rank + (size_t)li * E_ + e4);
  int4 sv = *(const int4*)(src + (size_t)li * E_ + e4);
  const int* op = offs + li * (U_ + 1);
  int* sp = ssrc + (size_t)li * EPL_;
  sp[op[dp.x] + rk.x] = sv.x;
  sp[op[dp.y] + rk.y] = sv.y;
  sp[op[dp.z] + rk.z] = sv.z;
  sp[op[dp.w] + rk.w] = sv.w;
}

// Pad+ug fill. Region A (t < L*U): per-u pad sentinels (end = start+cnt) +
// ug entries. Region B (1024 thr/layer): ssrc sentinel tails, FULL ug tail
// (replaces ug memset), arena zero row. Sentinel node id = N_ (both paths;
// arena remap maps N_ -> phys row 0 since wmask[N_]=lw0[N_]=0).
__global__ __launch_bounds__(256) void pad_fill_ug_k(
    const int* __restrict__ cnt, const int* __restrict__ offs,
    int* __restrict__ ssrc, int* __restrict__ ug, float4* __restrict__ zrow) {
  int t = blockIdx.x * 256 + threadIdx.x;
  if (t < L_ * U_) {
    int li = t / U_, u = t % U_;
    int start = offs[li * (U_ + 1) + u];
    int end = start + cnt[((size_t)li * U_ + u) * CNTS];
    int pend = offs[li * (U_ + 1) + u + 1];
    int* sp = ssrc + (size_t)li * EPL_;
    for (int p = end; p < pend; ++p) sp[p] = N_;
    int* ugp = ug + (size_t)li * EPLG_;
    for (int g = start >> 2; g < (pend >> 2); ++g) ugp[g] = u;
  } else {
    int t2 = t - L_ * U_;
    int li = t2 >> 10, j = t2 & 1023;
    if (li < L_) {
      int* sp = ssrc + (size_t)li * EPL_;
      int ptot = offs[li * (U_ + 1) + U_];
      if (j < 256) {
        int pos = ptot + j;
        if (pos < EPL_) sp[pos] = N_;
        sp[EPL_ - 256 + j] = N_;
      }
      int* ugp = ug + (size_t)li * EPLG_;
      for (int gq = (ptot >> 2) + j; gq < EPLG_; gq += 1024) ugp[gq] = -1;
      if (li == 0 && j < FH && zrow) zrow[j] = make_float4(0.f, 0.f, 0.f, 0.f);
    }
  }
}

// Remap ssrc node-ids -> phys rows valid BEFORE layer li (arena path only).
// Massively parallel; random wmask/posarr loads are TLP-hidden (r8 proven).
// Touches only initialized slots (p < ptot+256 or p >= EPL_-256).
__global__ __launch_bounds__(256) void remap_k(
    const int* __restrict__ offs, const int* __restrict__ wmask,
    const int* __restrict__ posarr, const int* __restrict__ lw0,
    int* __restrict__ ssrc) {
  int p = blockIdx.x * 256 + threadIdx.x;
  int li = blockIdx.y;
  if (p >= EPL_) return;
  int ptot = offs[li * (U_ + 1) + U_];
  if (p >= ptot + 256 && p < EPL_ - 256) return;
  int* sp = ssrc + (size_t)li * EPL_;
  int s = sp[p];  // node id in [0, N_]
  int m = wmask[s] & ((1 << li) - 1);
  int phys;
  if (m) {
    int lj = 31 - __clz(m);
    phys = DST0 + lj * U_ + posarr[lj * N_ + s];
  } else {
    phys = lw0[s];
  }
  sp[p] = phys;
}

// ---------------- Shared gather phase macro ----------------
#define PHASE(VACC, VLD, IDLD, IDPF, NUCUR)          \
  {                                                  \
    loadRows(VLD, IDLD);                             \
    IDPF = *(const int4*)(sp + 4 * CLG(g + 4));      \
    int nuCur = NUCUR;                               \
    NUCUR = ugp[CLG(g + 3) + 1];                     \
    accum(VACC);                                     \
    if (nuCur != curU) {                             \
      flushu(curU);                                  \
      if (g + 1 >= gstop) return;                    \
      curU = nuCur;                                  \
    }                                                \
    ++g;                                             \
  }

// ---------------- Arena-path compute (half batch, 1 KB rows) ----------------

// Gene init with LDS-transposed X loads (32B segments instead of 4B strided).
__global__ __launch_bounds__(256) void gene_a(
    const float* __restrict__ X, const float* __restrict__ w_in,
    const float* __restrict__ b_in, float4* __restrict__ h4, int half) {
  __shared__ float xs[8][33];
  int tid = threadIdx.x;
  int g0 = blockIdx.x * 8;
  {
    int b = tid >> 3, gi = tid & 7;
    xs[gi][b] = X[(size_t)(half * HBC + b) * G_ + g0 + gi];
  }
  __syncthreads();
  int b = tid & 31;
  int gi = tid >> 5;
  float x = xs[gi][b];
  int g = g0 + gi;
  float4 out[2];
  __half2* oh = reinterpret_cast<__half2*>(out);
#pragma unroll
  for (int k = 0; k < 8; ++k) {
    float r0 = fmaf(x, w_in[2 * k], b_in[2 * k]);
    float r1 = fmaf(x, w_in[2 * k + 1], b_in[2 * k + 1]);
    oh[k] = __float22half2_rn(make_float2(r0, r1));
  }
  h4[(size_t)(1 + g) * FH + b * 2] = out[0];
  h4[(size_t)(1 + g) * FH + b * 2 + 1] = out[1];
}

// Fused gather+dense (r8 proven): accumulate fp16 sums per u; at flush apply
// 16x16 W matmul (split across lane pairs), bias, tanh, write arena row.
__global__ __launch_bounds__(256, 2) void gfused_a(
    const float4* __restrict__ h4, const int* __restrict__ ug,
    const int* __restrict__ ssrc, const float* __restrict__ W,
    const float* __restrict__ bias, const int* __restrict__ dst_unique,
    float4* __restrict__ o4, int li) {
  __shared__ float Wlds[256];
  int tid = threadIdx.x;
  Wlds[tid] = W[li * 256 + tid];
  __syncthreads();
  int lane = tid & 63;
  int dh = lane & 1;
  int wv = __builtin_amdgcn_readfirstlane(blockIdx.x * 4 + (tid >> 6));
  const int* ugp = ug + (size_t)li * EPLG_;
  const int* sp = ssrc + (size_t)li * EPL_;
  const int* du = dst_unique + (size_t)li * U_;

  int g0 = wv * GPW, gend = g0 + GPW;
  int prevU = (g0 == 0) ? -2 : ugp[g0 - 1];
  int g = g0;
  while (g < gend && ugp[g] == prevU) ++g;
  if (g >= gend) return;
  int curU = ugp[g];
  if (curU < 0) return;
  int uend = ugp[gend - 1];
  int gstop;
  if (uend < 0) {
    gstop = g;
    while (ugp[gstop] >= 0) ++gstop;
  } else {
    gstop = gend;
    while (ugp[gstop] == uend) ++gstop;
  }

  __half2 acc[2][4];
  const __half2 z = __half2half2(__float2half(0.f));
#pragma unroll
  for (int j = 0; j < 2; ++j)
#pragma unroll
    for (int k = 0; k < 4; ++k) acc[j][k] = z;

  auto flushu = [&](int u) {
    int node = du[u];  // wave-uniform
    float biasv[8];
    {
      const float4* bp = (const float4*)(bias + (size_t)node * 16 + dh * 8);
      float4 q0 = bp[0], q1 = bp[1];
      biasv[0] = q0.x; biasv[1] = q0.y; biasv[2] = q0.z; biasv[3] = q0.w;
      biasv[4] = q1.x; biasv[5] = q1.y; biasv[6] = q1.z; biasv[7] = q1.w;
    }
    float a8[8];
#pragma unroll
    for (int k = 0; k < 4; ++k) {
      float2 f0 = __half22float2(acc[0][k]);
      float2 f1 = __half22float2(acc[1][k]);
      __half2 hv = __float22half2_rn(make_float2(f0.x + f1.x, f0.y + f1.y));
      float2 fa = __half22float2(hv);
      a8[2 * k] = fa.x; a8[2 * k + 1] = fa.y;
    }
    float pm[16];
#pragma unroll
    for (int j = 0; j < 16; ++j) pm[j] = 0.f;
#pragma unroll
    for (int dd = 0; dd < 8; ++dd) {
      float s = a8[dd];
      const float4* wr = (const float4*)&Wlds[(dh * 8 + dd) * 16];
      float4 w0 = wr[0], w1 = wr[1], w2 = wr[2], w3 = wr[3];
      pm[0] = fmaf(s, w0.x, pm[0]);  pm[1] = fmaf(s, w0.y, pm[1]);
      pm[2] = fmaf(s, w0.z, pm[2]);  pm[3] = fmaf(s, w0.w, pm[3]);
      pm[4] = fmaf(s, w1.x, pm[4]);  pm[5] = fmaf(s, w1.y, pm[5]);
      pm[6] = fmaf(s, w1.z, pm[6]);  pm[7] = fmaf(s, w1.w, pm[7]);
      pm[8] = fmaf(s, w2.x, pm[8]);  pm[9] = fmaf(s, w2.y, pm[9]);
      pm[10] = fmaf(s, w2.z, pm[10]); pm[11] = fmaf(s, w2.w, pm[11]);
      pm[12] = fmaf(s, w3.x, pm[12]); pm[13] = fmaf(s, w3.y, pm[13]);
      pm[14] = fmaf(s, w3.z, pm[14]); pm[15] = fmaf(s, w3.w, pm[15]);
    }
    float m8[8];
#pragma unroll
    for (int jj = 0; jj < 8; ++jj) {
      float s0 = pm[jj] + __shfl_xor(pm[jj], 1, 64);
      float s1 = pm[8 + jj] + __shfl_xor(pm[8 + jj], 1, 64);
      m8[jj] = dh ? s1 : s0;
    }
    float4 outv;
    __half2* ov = reinterpret_cast<__half2*>(&outv);
#pragma unroll
    for (int k = 0; k < 4; ++k) {
      ov[k] = __float22half2_rn(
          make_float2(tanh_fast(m8[2 * k] + biasv[2 * k]),
                      tanh_fast(m8[2 * k + 1] + biasv[2 * k + 1])));
    }
    o4[(size_t)(DST0 + li * U_ + u) * FH + lane] = outv;
#pragma unroll
    for (int j = 0; j < 2; ++j)
#pragma unroll
      for (int k = 0; k < 4; ++k) acc[j][k] = z;
  };

  auto loadRows = [&](float4 (&v)[4], int4 id) {
    v[0] = h4[(size_t)id.x * FH + lane];
    v[1] = h4[(size_t)id.y * FH + lane];
    v[2] = h4[(size_t)id.z * FH + lane];
    v[3] = h4[(size_t)id.w * FH + lane];
  };
  auto accum = [&](const float4 (&v)[4]) {
#pragma unroll
    for (int j = 0; j < 4; ++j) {
      const __half2* p = reinterpret_cast<const __half2*>(&v[j]);
#pragma unroll
      for (int k = 0; k < 4; ++k)
        acc[j & 1][k] = __hadd2(acc[j & 1][k], p[k]);
    }
  };
  auto CLG = [&](int q) { return (q < GCAP) ? q : GCAP - 1; };

  int4 id0 = *(const int4*)(sp + 4 * g);
  int4 id1 = *(const int4*)(sp + 4 * CLG(g + 1));
  int4 idP = *(const int4*)(sp + 4 * CLG(g + 2));
  int4 idQ = *(const int4*)(sp + 4 * CLG(g + 3));
  int4 idR;
  int nuA = ugp[g + 1];
  int nuB = ugp[CLG(g + 1) + 1];
  int nuC = ugp[CLG(g + 2) + 1];

  float4 va[4], vb[4], vc[4];
  loadRows(va, id0);
  loadRows(vb, id1);

  for (;;) {
    PHASE(va, vc, idP, idR, nuA)
    PHASE(vb, va, idQ, idP, nuB)
    PHASE(vc, vb, idR, idQ, nuC)
  }
}

// Head for one batch half: resolve final version per root via wmask.
__global__ __launch_bounds__(64) void head_a(
    const float4* __restrict__ h4, const float* __restrict__ W_head,
    const float* __restrict__ b_head, const int* __restrict__ root_ids,
    const int* __restrict__ wmask, const int* __restrict__ posarr,
    const int* __restrict__ lw0, int half, float* __restrict__ out) {
  int bl = blockIdx.x;
  int r = threadIdx.x;
  int node = root_ids[r];
  int m = wmask[node];
  int phys;
  if (m) {
    int lj = 31 - __clz(m);
    phys = DST0 + lj * U_ + posarr[lj * N_ + node];
  } else {
    phys = lw0[node];
  }
  float4 p0 = h4[(size_t)phys * FH + bl * 2];
  float4 p1 = h4[(size_t)phys * FH + bl * 2 + 1];
  float v[16];
  const __half2* ph0 = reinterpret_cast<const __half2*>(&p0);
  const __half2* ph1 = reinterpret_cast<const __half2*>(&p1);
#pragma unroll
  for (int k = 0; k < 4; ++k) {
    float2 f0 = __half22float2(ph0[k]);
    float2 f1 = __half22float2(ph1[k]);
    v[2 * k] = f0.x; v[2 * k + 1] = f0.y;
    v[8 + 2 * k] = f1.x; v[8 + 2 * k + 1] = f1.y;
  }
  float acc0 = 0.f, acc1 = 0.f;
#pragma unroll
  for (int d = 0; d < 16; ++d) {
    acc0 = fmaf(v[d], W_head[r * 16 + d], acc0);
    acc1 = fmaf(v[d], W_head[1024 + r * 16 + d], acc1);
  }
  for (int off = 32; off; off >>= 1) {
    acc0 += __shfl_down(acc0, off, 64);
    acc1 += __shfl_down(acc1, off, 64);
  }
  if (r == 0) {
    int gb = half * HBC + bl;
    out[gb * 2 + 0] = acc0 + b_head[0];
    out[gb * 2 + 1] = acc1 + b_head[1];
  }
}

// ---------------- Classic fallback (round-5 proven, 2 KB rows) --------------

__global__ __launch_bounds__(256) void gene_c(
    const float* __restrict__ X, const float* __restrict__ w_in,
    const float* __restrict__ b_in, const int* __restrict__ gene_map,
    float4* __restrict__ h4) {
  int t = blockIdx.x * 256 + threadIdx.x;
  if (t >= G_ * BC) return;
  int b = t % BC;
  int g = t / BC;
  float x = X[b * G_ + g];
  int node = gene_map[g];
  float4 out[2];
  __half2* oh = reinterpret_cast<__half2*>(out);
#pragma unroll
  for (int k = 0; k < 8; ++k) {
    float r0 = fmaf(x, w_in[2 * k], b_in[2 * k]);
    float r1 = fmaf(x, w_in[2 * k + 1], b_in[2 * k + 1]);
    oh[k] = __float22half2_rn(make_float2(r0, r1));
  }
  h4[(size_t)node * F + b * 2] = out[0];
  h4[(size_t)node * F + b * 2 + 1] = out[1];
}

__global__ __launch_bounds__(256, 2) void gather_c(
    const float4* __restrict__ h4, const int* __restrict__ ug,
    const int* __restrict__ ssrc, float4* __restrict__ agg4, int li) {
  int tid = threadIdx.x;
  int lane = tid & 63;
  int wv = __builtin_amdgcn_readfirstlane(blockIdx.x * 4 + (tid >> 6));
  const int* ugp = ug + (size_t)li * EPLG_;
  const int* sp = ssrc + (size_t)li * EPL_;

  int g0 = wv * GPW, gend = g0 + GPW;
  int prevU = (g0 == 0) ? -2 : ugp[g0 - 1];
  int g = g0;
  while (g < gend && ugp[g] == prevU) ++g;
  if (g >= gend) return;
  int curU = ugp[g];
  if (curU < 0) return;
  int uend = ugp[gend - 1];
  int gstop;
  if (uend < 0) {
    gstop = g;
    while (ugp[gstop] >= 0) ++gstop;
  } else {
    gstop = gend;
    while (ugp[gstop] == uend) ++gstop;
  }

  __half2 acc[2][2][4];
  const __half2 z = __half2half2(__float2half(0.f));
#pragma unroll
  for (int j = 0; j < 2; ++j)
#pragma unroll
    for (int r = 0; r < 2; ++r)
#pragma unroll
      for (int k = 0; k < 4; ++k) acc[j][r][k] = z;

  auto flushu = [&](int u) {
#pragma unroll
    for (int r = 0; r < 2; ++r) {
      float4 outv;
      __half2* ov = reinterpret_cast<__half2*>(&outv);
#pragma unroll
      for (int k = 0; k < 4; ++k) {
        float2 f0 = __half22float2(acc[0][r][k]);
        float2 f1 = __half22float2(acc[1][r][k]);
        ov[k] = __float22half2_rn(make_float2(f0.x + f1.x, f0.y + f1.y));
      }
      agg4[(size_t)u * F + lane + r * 64] = outv;
    }
#pragma unroll
    for (int j = 0; j < 2; ++j)
#pragma unroll
      for (int r = 0; r < 2; ++r)
#pragma unroll
        for (int k = 0; k < 4; ++k) acc[j][r][k] = z;
  };
  auto loadRows = [&](float4 (&v)[4][2], int4 id) {
    v[0][0] = h4[(size_t)id.x * F + lane]; v[0][1] = h4[(size_t)id.x * F + lane + 64];
    v[1][0] = h4[(size_t)id.y * F + lane]; v[1][1] = h4[(size_t)id.y * F + lane + 64];
    v[2][0] = h4[(size_t)id.z * F + lane]; v[2][1] = h4[(size_t)id.z * F + lane + 64];
    v[3][0] = h4[(size_t)id.w * F + lane]; v[3][1] = h4[(size_t)id.w * F + lane + 64];
  };
  auto accum = [&](const float4 (&v)[4][2]) {
#pragma unroll
    for (int j = 0; j < 4; ++j)
#pragma unroll
      for (int r = 0; r < 2; ++r) {
        const __half2* p = reinterpret_cast<const __half2*>(&v[j][r]);
#pragma unroll
        for (int k = 0; k < 4; ++k)
          acc[j & 1][r][k] = __hadd2(acc[j & 1][r][k], p[k]);
      }
  };
  auto CLG = [&](int q) { return (q < GCAP) ? q : GCAP - 1; };

  int4 id0 = *(const int4*)(sp + 4 * g);
  int4 id1 = *(const int4*)(sp + 4 * CLG(g + 1));
  int4 idP = *(const int4*)(sp + 4 * CLG(g + 2));
  int4 idQ = *(const int4*)(sp + 4 * CLG(g + 3));
  int4 idR;
  int nuA = ugp[g + 1];
  int nuB = ugp[CLG(g + 1) + 1];
  int nuC = ugp[CLG(g + 2) + 1];

  float4 va[4][2], vb[4][2], vc[4][2];
  loadRows(va, id0);
  loadRows(vb, id1);

  for (;;) {
    PHASE(va, vc, idP, idR, nuA)
    PHASE(vb, va, idQ, idP, nuB)
    PHASE(vc, vb, idR, idQ, nuC)
  }
}
#undef PHASE

__global__ __launch_bounds__(256) void dense_c(
    const float4* __restrict__ agg4, const float* __restrict__ W,
    const float* __restrict__ bias, const int* __restrict__ dst_unique,
    float4* __restrict__ h4, int li) {
  __shared__ float Wlds[256];
  int tid = threadIdx.x;
  Wlds[tid] = W[li * 256 + tid];
  __syncthreads();
  int u = __builtin_amdgcn_readfirstlane(blockIdx.x * 4 + (tid >> 6));
  int b = tid & 63;
  float4 c0 = agg4[(size_t)u * F + b * 2];
  float4 c1 = agg4[(size_t)u * F + b * 2 + 1];
  float a[16];
  {
    const __half2* p0 = reinterpret_cast<const __half2*>(&c0);
    const __half2* p1 = reinterpret_cast<const __half2*>(&c1);
#pragma unroll
    for (int k = 0; k < 4; ++k) {
      float2 f0 = __half22float2(p0[k]);
      float2 f1 = __half22float2(p1[k]);
      a[2 * k] = f0.x; a[2 * k + 1] = f0.y;
      a[8 + 2 * k] = f1.x; a[8 + 2 * k + 1] = f1.y;
    }
  }
  float m[16];
#pragma unroll
  for (int j = 0; j < 16; ++j) m[j] = 0.f;
#pragma unroll
  for (int d = 0; d < 16; ++d) {
    float s = a[d];
    const float4* wr = (const float4*)&Wlds[d * 16];
    float4 w0 = wr[0], w1 = wr[1], w2 = wr[2], w3 = wr[3];
    m[0] = fmaf(s, w0.x, m[0]);  m[1] = fmaf(s, w0.y, m[1]);
    m[2] = fmaf(s, w0.z, m[2]);  m[3] = fmaf(s, w0.w, m[3]);
    m[4] = fmaf(s, w1.x, m[4]);  m[5] = fmaf(s, w1.y, m[5]);
    m[6] = fmaf(s, w1.z, m[6]);  m[7] = fmaf(s, w1.w, m[7]);
    m[8] = fmaf(s, w2.x, m[8]);  m[9] = fmaf(s, w2.y, m[9]);
    m[10] = fmaf(s, w2.z, m[10]); m[11] = fmaf(s, w2.w, m[11]);
    m[12] = fmaf(s, w3.x, m[12]); m[13] = fmaf(s, w3.y, m[13]);
    m[14] = fmaf(s, w3.z, m[14]); m[15] = fmaf(s, w3.w, m[15]);
  }
  int node = dst_unique[li * U_ + u];
  const float4* bp = (const float4*)(bias + (size_t)node * 16);
  float4 b0 = bp[0], b1 = bp[1], b2 = bp[2], b3 = bp[3];
  float bb[16] = {b0.x, b0.y, b0.z, b0.w, b1.x, b1.y, b1.z, b1.w,
                  b2.x, b2.y, b2.z, b2.w, b3.x, b3.y, b3.z, b3.w};
  float4 o0, o1;
  __half2* ov0 = reinterpret_cast<__half2*>(&o0);
  __half2* ov1 = reinterpret_cast<__half2*>(&o1);
#pragma unroll
  for (int k = 0; k < 4; ++k) {
    ov0[k] = __float22half2_rn(make_float2(tanh_fast(m[2 * k] + bb[2 * k]),
                                           tanh_fast(m[2 * k + 1] + bb[2 * k + 1])));
    ov1[k] = __float22half2_rn(make_float2(tanh_fast(m[8 + 2 * k] + bb[8 + 2 * k]),
                                           tanh_fast(m[8 + 2 * k + 1] + bb[8 + 2 * k + 1])));
  }
  h4[(size_t)node * F + b * 2] = o0;
  h4[(size_t)node * F + b * 2 + 1] = o1;
}

__global__ __launch_bounds__(64) void head_c(
    const float4* __restrict__ h4, const float* __restrict__ W_head,
    const float* __restrict__ b_head, const int* __restrict__ root_ids,
    float* __restrict__ out) {
  int bl = blockIdx.x;
  int r = threadIdx.x;
  int node = root_ids[r];
  float4 p0 = h4[(size_t)node * F + bl * 2];
  float4 p1 = h4[(size_t)node * F + bl * 2 + 1];
  float v[16];
  const __half2* ph0 = reinterpret_cast<const __half2*>(&p0);
  const __half2* ph1 = reinterpret_cast<const __half2*>(&p1);
#pragma unroll
  for (int k = 0; k < 4; ++k) {
    float2 f0 = __half22float2(ph0[k]);
    float2 f1 = __half22float2(ph1[k]);
    v[2 * k] = f0.x; v[2 * k + 1] = f0.y;
    v[8 + 2 * k] = f1.x; v[8 + 2 * k + 1] = f1.y;
  }
  float acc0 = 0.f, acc1 = 0.f;
#pragma unroll
  for (int d = 0; d < 16; ++d) {
    acc0 = fmaf(v[d], W_head[r * 16 + d], acc0);
    acc1 = fmaf(v[d], W_head[1024 + r * 16 + d], acc1);
  }
  for (int off = 32; off; off >>= 1) {
    acc0 += __shfl_down(acc0, off, 64);
    acc1 += __shfl_down(acc1, off, 64);
  }
  if (r == 0) {
    out[bl * 2 + 0] = acc0 + b_head[0];
    out[bl * 2 + 1] = acc1 + b_head[1];
  }
}

__global__ void zero_out_k(float* out, int n) {
  int t = blockIdx.x * 256 + threadIdx.x;
  if (t < n) out[t] = 0.f;
}

// ---------------- Host side ----------------

static size_t arena_bytes() {
  return (size_t)AROWS * FH * 16 +
         (size_t)L_ * U_ * CNTS * 4 +     // cnt (line-padded)
         (size_t)2 * (N_ + 1) * 4 +       // wmask + lw0 (contiguous w/ cnt)
         (size_t)L_ * (U_ + 1) * 4 +      // offs
         (size_t)L_ * E_ * 4 +            // rank
         (size_t)L_ * EPL_ * 4 +          // ssrc
         (size_t)L_ * EPLG_ * 4 +         // ug
         (size_t)L_ * N_ * 4;             // posarr
}
static size_t classic_bytes() {
  return (size_t)(N_ + 1) * F * 16 + (size_t)U_ * F * 16 +
         (size_t)L_ * U_ * CNTS * 4 + (size_t)L_ * (U_ + 1) * 4 +
         (size_t)L_ * E_ * 4 + (size_t)L_ * EPL_ * 4 + (size_t)L_ * EPLG_ * 4;
}

extern "C" void kernel_launch(void* const* d_in, const int* in_sizes, int n_in,
                              void* d_out, int out_size, void* d_ws, size_t ws_size,
                              hipStream_t stream) {
  const float* X = (const float*)d_in[0];
  const float* w_in = (const float*)d_in[1];
  const float* b_in = (const float*)d_in[2];
  const float* W = (const float*)d_in[3];
  const float* bias = (const float*)d_in[4];
  const float* W_head = (const float*)d_in[5];
  const float* b_head = (const float*)d_in[6];
  const int* gene_map = (const int*)d_in[7];
  const int* src = (const int*)d_in[8];
  const int* dst_pos = (const int*)d_in[9];
  const int* dst_unique = (const int*)d_in[10];
  const int* root_ids = (const int*)d_in[11];
  float* out = (float*)d_out;

  dim3 e4grid(HISTB4, L_);
  const int pf_grid = (L_ * U_ + L_ * 1024 + 255) / 256;
  const int gather_grid = (SW + 3) / 4;

  if (ws_size >= arena_bytes()) {
    // ---------- Arena path: fused gather+dense, two batch halves ----------
    char* ws = (char*)d_ws;
    float4* arena = (float4*)ws;
    size_t off = (size_t)AROWS * FH * 16;
    int* cnt = (int*)(ws + off);    off += (size_t)L_ * U_ * CNTS * 4;
    int* wmask = (int*)(ws + off);  off += (size_t)(N_ + 1) * 4;
    int* lw0 = (int*)(ws + off);    off += (size_t)(N_ + 1) * 4;
    int* offs = (int*)(ws + off);   off += (size_t)L_ * (U_ + 1) * 4;
    int* rank = (int*)(ws + off);   off += (size_t)L_ * E_ * 4;
    int* ssrc = (int*)(ws + off);   off += (size_t)L_ * EPL_ * 4;
    int* ug = (int*)(ws + off);     off += (size_t)L_ * EPLG_ * 4;
    int* posarr = (int*)(ws + off);

    // single memset: cnt | wmask | lw0 contiguous
    hipMemsetAsync(cnt, 0,
                   (size_t)L_ * U_ * CNTS * 4 + (size_t)2 * (N_ + 1) * 4,
                   stream);
    dim3 hmgrid(HISTB4 + (L_ * U_ + G_ + 255) / 256, L_);
    hist_mark_k<<<hmgrid, 256, 0, stream>>>(dst_pos, cnt, rank, dst_unique,
                                            gene_map, wmask, posarr, lw0);
    scan_kernel<<<L_, 1024, 0, stream>>>(cnt, offs);
    scatter_kernel<<<e4grid, 256, 0, stream>>>(dst_pos, src, offs, rank, ssrc);
    pad_fill_ug_k<<<pf_grid, 256, 0, stream>>>(cnt, offs, ssrc, ug, arena);
    dim3 rgrid((EPL_ + 255) / 256, L_);
    remap_k<<<rgrid, 256, 0, stream>>>(offs, wmask, posarr, lw0, ssrc);

    for (int half = 0; half < 2; ++half) {
      gene_a<<<G_ / 8, 256, 0, stream>>>(X, w_in, b_in, arena, half);
      for (int li = 0; li < L_; ++li) {
        gfused_a<<<gather_grid, 256, 0, stream>>>(arena, ug, ssrc, W, bias,
                                                  dst_unique, arena, li);
      }
      head_a<<<HBC, 64, 0, stream>>>(arena, W_head, b_head, root_ids, wmask,
                                     posarr, lw0, half, out);
    }
  } else if (ws_size >= classic_bytes()) {
    // ---------- Classic path (round-5 proven structure) ----------
    const size_t h_bytes = (size_t)(N_ + 1) * F * 16;
    const size_t agg_bytes = (size_t)U_ * F * 16;
    char* ws = (char*)d_ws;
    float4* h4 = (float4*)ws;
    float4* agg4 = (float4*)(ws + h_bytes);
    size_t off = h_bytes + agg_bytes;
    int* cnt = (int*)(ws + off);   off += (size_t)L_ * U_ * CNTS * 4;
    int* offs = (int*)(ws + off);  off += (size_t)L_ * (U_ + 1) * 4;
    int* rank = (int*)(ws + off);  off += (size_t)L_ * E_ * 4;
    int* ssrc = (int*)(ws + off);  off += (size_t)L_ * EPL_ * 4;
    int* ug = (int*)(ws + off);

    hipMemsetAsync(cnt, 0, (size_t)L_ * U_ * CNTS * 4, stream);
    hipMemsetAsync(h4, 0, h_bytes, stream);
    hist_mark_k<<<e4grid, 256, 0, stream>>>(dst_pos, cnt, rank, nullptr,
                                            nullptr, nullptr, nullptr, nullptr);
    scan_kernel<<<L_, 1024, 0, stream>>>(cnt, offs);
    scatter_kernel<<<e4grid, 256, 0, stream>>>(dst_pos, src, offs, rank, ssrc);
    pad_fill_ug_k<<<pf_grid, 256, 0, stream>>>(cnt, offs, ssrc, ug, nullptr);
    gene_c<<<(G_ * BC + 255) / 256, 256, 0, stream>>>(X, w_in, b_in, gene_map, h4);
    const int dense_grid = U_ * BC / 256;
    for (int li = 0; li < L_; ++li) {
      gather_c<<<gather_grid, 256, 0, stream>>>(h4, ug, ssrc, agg4, li);
      dense_c<<<dense_grid, 256, 0, stream>>>(agg4, W, bias, dst_unique, h4, li);
    }
    head_c<<<BC, 64, 0, stream>>>(h4, W_head, b_head, root_ids, out);
  } else {
    zero_out_k<<<(out_size + 255) / 256, 256, 0, stream>>>(out, out_size);
  }
}

// Round 12
// 552.793 us; speedup vs baseline: 1.0416x; 1.0416x over previous
//
#include <hip/hip_runtime.h>
#include <hip/hip_fp16.h>
#include <cmath>

// Problem constants
constexpr int B_ = 64, N_ = 50000, L_ = 8, E_ = 100000, U_ = 20000, G_ = 20000, R_ = 64, D_ = 16, C_ = 2;
constexpr int EPL_ = E_ + 3 * U_ + 4096;  // padded edge slots per layer
constexpr int EPLG_ = EPL_ / 4 + 64;      // group slots per layer
constexpr int GPW = 8;                    // groups per wave span (32 edges)
constexpr int GCAP = EPL_ / 4;
constexpr int SW = (GCAP + GPW - 1) / GPW;

// LDS counting-sort geometry (r11 lesson: global atomics ~14G/s is a hard
// floor -> use LDS histograms; zero global atomics in hist/scatter).
constexpr int NB = 32;                    // hist blocks per layer
constexpr int EB = E_ / NB;               // 3125 edges per block (exact)
constexpr int URB = U_ / 2;               // u-range per LDS sub-pass (40KB)

// Classic geometry (fallback): full batch, 2 KB rows.
constexpr int BC = 64;
constexpr int F = BC * 2;

// Arena geometry: HALF batch, 1 KB rows -> versioned arena fits 256 MiB ws.
// phys row 0 = zero row; rows 1..G = gene rows; row DST0+li*U+u = layer-li
// output for dst u. ssrc remapped (separate pass) to phys rows valid BEFORE
// layer li -> same-layer reads/writes disjoint. Two passes over batch halves.
constexpr int HBC = 32;
constexpr int FH = HBC * 2;               // 64 float4 chunks/row (1 KB)
constexpr int DST0 = 1 + G_;
constexpr int AROWS = DST0 + L_ * U_;     // 180001 rows = 184.3 MB

__device__ __forceinline__ float tanh_fast(float x) {
  float e = __expf(2.0f * x);
  return 1.0f - 2.0f * __builtin_amdgcn_rcpf(e + 1.0f);
}

// ---------------- CSR build (LDS counting sort) ----------------

// Pass A: per-(layer, block-of-3125-edges) LDS histogram over two u-ranges.
// rank[e] = block-local rank (LDS atomic return); part[li][b][u] = count.
__global__ __launch_bounds__(256) void hist_lds_k(
    const int* __restrict__ dst_pos, int* __restrict__ rank,
    int* __restrict__ part) {
  __shared__ int hcnt[URB];  // 40 KB
  int li = blockIdx.y, b = blockIdx.x;
  int tid = threadIdx.x;
  int e0 = b * EB, e1 = e0 + EB;
  const int* dp = dst_pos + (size_t)li * E_;
  int* rk = rank + (size_t)li * E_;
#pragma unroll
  for (int r = 0; r < 2; ++r) {
    int ub = r * URB;
    for (int i = tid; i < URB; i += 256) hcnt[i] = 0;
    __syncthreads();
    for (int e = e0 + tid; e < e1; e += 256) {
      int u = dp[e] - ub;
      if ((unsigned)u < (unsigned)URB) rk[e] = atomicAdd(&hcnt[u], 1);
    }
    __syncthreads();
    int* pp = part + ((size_t)li * NB + b) * U_ + ub;
    for (int i = tid; i < URB; i += 256) pp[i] = hcnt[i];
    __syncthreads();
  }
}

// Pass B: thread per u: in-place exclusive scan of part over blocks
// (part[li][b][u] -> base), total -> cnt. All accesses coalesced in u.
__global__ __launch_bounds__(256) void sumpart_k(
    int* __restrict__ part, int* __restrict__ cnt) {
  int u = blockIdx.x * 256 + threadIdx.x;
  int li = blockIdx.y;
  if (u >= U_) return;
  int s = 0;
#pragma unroll 4
  for (int b = 0; b < NB; ++b) {
    size_t idx = ((size_t)li * NB + b) * U_ + u;
    int v = part[idx];
    part[idx] = s;
    s += v;
  }
  cnt[li * U_ + u] = s;
}

// Scan (8 blocks): counts padded to mult of 4, empty u -> 4 slots.
__global__ __launch_bounds__(1024) void scan_kernel(
    const int* __restrict__ cnt, int* __restrict__ offs) {
  __shared__ int sums[1024];
  int li = blockIdx.x, t = threadIdx.x;
  int base = t * 20;
  int v[20];
  int s = 0;
#pragma unroll
  for (int i = 0; i < 20; ++i) {
    int idx = base + i;
    int c = (idx < U_) ? cnt[li * U_ + idx] : -1;
    int pc = (c < 0) ? 0 : ((c == 0) ? 4 : ((c + 3) & ~3));
    v[i] = s;
    s += pc;
  }
  sums[t] = s;
  __syncthreads();
  for (int off = 1; off < 1024; off <<= 1) {
    int o = (t >= off) ? sums[t - off] : 0;
    __syncthreads();
    sums[t] += o;
    __syncthreads();
  }
  int excl = sums[t] - s;
#pragma unroll
  for (int i = 0; i < 20; ++i) {
    int idx = base + i;
    if (idx < U_) offs[li * (U_ + 1) + idx] = excl + v[i];
  }
  if (t == 1023) offs[li * (U_ + 1) + U_] = sums[1023];
}

// Atomic-free scatter, 4 edges/thread:
// position = offs[u] + blockbase part[li][b(e)][u] + local rank.
__global__ __launch_bounds__(256) void scatter_kernel(
    const int* __restrict__ dst_pos, const int* __restrict__ src,
    const int* __restrict__ offs, const int* __restrict__ part,
    const int* __restrict__ rank, int* __restrict__ ssrc) {
  int e4 = (blockIdx.x * 256 + threadIdx.x) * 4;
  int li = blockIdx.y;
  if (e4 >= E_) return;
  int4 dp = *(const int4*)(dst_pos + (size_t)li * E_ + e4);
  int4 rk = *(const int4*)(rank + (size_t)li * E_ + e4);
  int4 sv = *(const int4*)(src + (size_t)li * E_ + e4);
  const int* op = offs + li * (U_ + 1);
  const int* pb = part + (size_t)li * NB * U_;
  int* sp = ssrc + (size_t)li * EPL_;
  int b0 = (e4 + 0) / EB, b1 = (e4 + 1) / EB;
  int b2 = (e4 + 2) / EB, b3 = (e4 + 3) / EB;
  sp[op[dp.x] + pb[(size_t)b0 * U_ + dp.x] + rk.x] = sv.x;
  sp[op[dp.y] + pb[(size_t)b1 * U_ + dp.y] + rk.y] = sv.y;
  sp[op[dp.z] + pb[(size_t)b2 * U_ + dp.z] + rk.z] = sv.z;
  sp[op[dp.w] + pb[(size_t)b3 * U_ + dp.w] + rk.w] = sv.w;
}

// Pad+ug fill. Region A (t < L*U): per-u pad sentinels + ug entries.
// Region B (1024 thr/layer): ssrc sentinel tails, FULL ug tail, arena zero
// row. Sentinel node id = N_ (arena remap maps N_ -> phys row 0).
__global__ __launch_bounds__(256) void pad_fill_ug_k(
    const int* __restrict__ cnt, const int* __restrict__ offs,
    int* __restrict__ ssrc, int* __restrict__ ug, float4* __restrict__ zrow) {
  int t = blockIdx.x * 256 + threadIdx.x;
  if (t < L_ * U_) {
    int li = t / U_, u = t % U_;
    int start = offs[li * (U_ + 1) + u];
    int end = start + cnt[li * U_ + u];
    int pend = offs[li * (U_ + 1) + u + 1];
    int* sp = ssrc + (size_t)li * EPL_;
    for (int p = end; p < pend; ++p) sp[p] = N_;
    int* ugp = ug + (size_t)li * EPLG_;
    for (int g = start >> 2; g < (pend >> 2); ++g) ugp[g] = u;
  } else {
    int t2 = t - L_ * U_;
    int li = t2 >> 10, j = t2 & 1023;
    if (li < L_) {
      int* sp = ssrc + (size_t)li * EPL_;
      int ptot = offs[li * (U_ + 1) + U_];
      if (j < 256) {
        int pos = ptot + j;
        if (pos < EPL_) sp[pos] = N_;
        sp[EPL_ - 256 + j] = N_;
      }
      int* ugp = ug + (size_t)li * EPLG_;
      for (int gq = (ptot >> 2) + j; gq < EPLG_; gq += 1024) ugp[gq] = -1;
      if (li == 0 && j < FH && zrow) zrow[j] = make_float4(0.f, 0.f, 0.f, 0.f);
    }
  }
}

// Versioning mark (arena path; r8-proven standalone form).
__global__ __launch_bounds__(256) void mark_k(
    const int* __restrict__ dst_unique, const int* __restrict__ gene_map,
    int* __restrict__ wmask, int* __restrict__ posarr, int* __restrict__ lw0) {
  int t = blockIdx.x * 256 + threadIdx.x;
  if (t < L_ * U_) {
    int li = t / U_, u = t % U_;
    int n = dst_unique[t];
    posarr[li * N_ + n] = u;
    atomicOr(&wmask[n], 1 << li);
  } else {
    int g = t - L_ * U_;
    if (g < G_) lw0[gene_map[g]] = 1 + g;
  }
}

// Remap ssrc node-ids -> phys rows valid BEFORE layer li (arena path only).
// Touches only initialized slots (p < ptot+256 or p >= EPL_-256).
__global__ __launch_bounds__(256) void remap_k(
    const int* __restrict__ offs, const int* __restrict__ wmask,
    const int* __restrict__ posarr, const int* __restrict__ lw0,
    int* __restrict__ ssrc) {
  int p = blockIdx.x * 256 + threadIdx.x;
  int li = blockIdx.y;
  if (p >= EPL_) return;
  int ptot = offs[li * (U_ + 1) + U_];
  if (p >= ptot + 256 && p < EPL_ - 256) return;
  int* sp = ssrc + (size_t)li * EPL_;
  int s = sp[p];  // node id in [0, N_]
  int m = wmask[s] & ((1 << li) - 1);
  int phys;
  if (m) {
    int lj = 31 - __clz(m);
    phys = DST0 + lj * U_ + posarr[lj * N_ + s];
  } else {
    phys = lw0[s];
  }
  sp[p] = phys;
}

// ---------------- Shared gather phase macro ----------------
#define PHASE(VACC, VLD, IDLD, IDPF, NUCUR)          \
  {                                                  \
    loadRows(VLD, IDLD);                             \
    IDPF = *(const int4*)(sp + 4 * CLG(g + 4));      \
    int nuCur = NUCUR;                               \
    NUCUR = ugp[CLG(g + 3) + 1];                     \
    accum(VACC);                                     \
    if (nuCur != curU) {                             \
      flushu(curU);                                  \
      if (g + 1 >= gstop) return;                    \
      curU = nuCur;                                  \
    }                                                \
    ++g;                                             \
  }

// ---------------- Arena-path compute (half batch, 1 KB rows) ----------------

// Gene init with LDS-transposed X loads (32B segments instead of 4B strided).
__global__ __launch_bounds__(256) void gene_a(
    const float* __restrict__ X, const float* __restrict__ w_in,
    const float* __restrict__ b_in, float4* __restrict__ h4, int half) {
  __shared__ float xs[8][33];
  int tid = threadIdx.x;
  int g0 = blockIdx.x * 8;
  {
    int b = tid >> 3, gi = tid & 7;
    xs[gi][b] = X[(size_t)(half * HBC + b) * G_ + g0 + gi];
  }
  __syncthreads();
  int b = tid & 31;
  int gi = tid >> 5;
  float x = xs[gi][b];
  int g = g0 + gi;
  float4 out[2];
  __half2* oh = reinterpret_cast<__half2*>(out);
#pragma unroll
  for (int k = 0; k < 8; ++k) {
    float r0 = fmaf(x, w_in[2 * k], b_in[2 * k]);
    float r1 = fmaf(x, w_in[2 * k + 1], b_in[2 * k + 1]);
    oh[k] = __float22half2_rn(make_float2(r0, r1));
  }
  h4[(size_t)(1 + g) * FH + b * 2] = out[0];
  h4[(size_t)(1 + g) * FH + b * 2 + 1] = out[1];
}

// Fused gather+dense (r8 proven): accumulate fp16 sums per u; at flush apply
// 16x16 W matmul (split across lane pairs), bias, tanh, write arena row.
__global__ __launch_bounds__(256, 2) void gfused_a(
    const float4* __restrict__ h4, const int* __restrict__ ug,
    const int* __restrict__ ssrc, const float* __restrict__ W,
    const float* __restrict__ bias, const int* __restrict__ dst_unique,
    float4* __restrict__ o4, int li) {
  __shared__ float Wlds[256];
  int tid = threadIdx.x;
  Wlds[tid] = W[li * 256 + tid];
  __syncthreads();
  int lane = tid & 63;
  int dh = lane & 1;
  int wv = __builtin_amdgcn_readfirstlane(blockIdx.x * 4 + (tid >> 6));
  const int* ugp = ug + (size_t)li * EPLG_;
  const int* sp = ssrc + (size_t)li * EPL_;
  const int* du = dst_unique + (size_t)li * U_;

  int g0 = wv * GPW, gend = g0 + GPW;
  int prevU = (g0 == 0) ? -2 : ugp[g0 - 1];
  int g = g0;
  while (g < gend && ugp[g] == prevU) ++g;
  if (g >= gend) return;
  int curU = ugp[g];
  if (curU < 0) return;
  int uend = ugp[gend - 1];
  int gstop;
  if (uend < 0) {
    gstop = g;
    while (ugp[gstop] >= 0) ++gstop;
  } else {
    gstop = gend;
    while (ugp[gstop] == uend) ++gstop;
  }

  __half2 acc[2][4];
  const __half2 z = __half2half2(__float2half(0.f));
#pragma unroll
  for (int j = 0; j < 2; ++j)
#pragma unroll
    for (int k = 0; k < 4; ++k) acc[j][k] = z;

  auto flushu = [&](int u) {
    int node = du[u];  // wave-uniform
    float biasv[8];
    {
      const float4* bp = (const float4*)(bias + (size_t)node * 16 + dh * 8);
      float4 q0 = bp[0], q1 = bp[1];
      biasv[0] = q0.x; biasv[1] = q0.y; biasv[2] = q0.z; biasv[3] = q0.w;
      biasv[4] = q1.x; biasv[5] = q1.y; biasv[6] = q1.z; biasv[7] = q1.w;
    }
    float a8[8];
#pragma unroll
    for (int k = 0; k < 4; ++k) {
      float2 f0 = __half22float2(acc[0][k]);
      float2 f1 = __half22float2(acc[1][k]);
      __half2 hv = __float22half2_rn(make_float2(f0.x + f1.x, f0.y + f1.y));
      float2 fa = __half22float2(hv);
      a8[2 * k] = fa.x; a8[2 * k + 1] = fa.y;
    }
    float pm[16];
#pragma unroll
    for (int j = 0; j < 16; ++j) pm[j] = 0.f;
#pragma unroll
    for (int dd = 0; dd < 8; ++dd) {
      float s = a8[dd];
      const float4* wr = (const float4*)&Wlds[(dh * 8 + dd) * 16];
      float4 w0 = wr[0], w1 = wr[1], w2 = wr[2], w3 = wr[3];
      pm[0] = fmaf(s, w0.x, pm[0]);  pm[1] = fmaf(s, w0.y, pm[1]);
      pm[2] = fmaf(s, w0.z, pm[2]);  pm[3] = fmaf(s, w0.w, pm[3]);
      pm[4] = fmaf(s, w1.x, pm[4]);  pm[5] = fmaf(s, w1.y, pm[5]);
      pm[6] = fmaf(s, w1.z, pm[6]);  pm[7] = fmaf(s, w1.w, pm[7]);
      pm[8] = fmaf(s, w2.x, pm[8]);  pm[9] = fmaf(s, w2.y, pm[9]);
      pm[10] = fmaf(s, w2.z, pm[10]); pm[11] = fmaf(s, w2.w, pm[11]);
      pm[12] = fmaf(s, w3.x, pm[12]); pm[13] = fmaf(s, w3.y, pm[13]);
      pm[14] = fmaf(s, w3.z, pm[14]); pm[15] = fmaf(s, w3.w, pm[15]);
    }
    float m8[8];
#pragma unroll
    for (int jj = 0; jj < 8; ++jj) {
      float s0 = pm[jj] + __shfl_xor(pm[jj], 1, 64);
      float s1 = pm[8 + jj] + __shfl_xor(pm[8 + jj], 1, 64);
      m8[jj] = dh ? s1 : s0;
    }
    float4 outv;
    __half2* ov = reinterpret_cast<__half2*>(&outv);
#pragma unroll
    for (int k = 0; k < 4; ++k) {
      ov[k] = __float22half2_rn(
          make_float2(tanh_fast(m8[2 * k] + biasv[2 * k]),
                      tanh_fast(m8[2 * k + 1] + biasv[2 * k + 1])));
    }
    o4[(size_t)(DST0 + li * U_ + u) * FH + lane] = outv;
#pragma unroll
    for (int j = 0; j < 2; ++j)
#pragma unroll
      for (int k = 0; k < 4; ++k) acc[j][k] = z;
  };

  auto loadRows = [&](float4 (&v)[4], int4 id) {
    v[0] = h4[(size_t)id.x * FH + lane];
    v[1] = h4[(size_t)id.y * FH + lane];
    v[2] = h4[(size_t)id.z * FH + lane];
    v[3] = h4[(size_t)id.w * FH + lane];
  };
  auto accum = [&](const float4 (&v)[4]) {
#pragma unroll
    for (int j = 0; j < 4; ++j) {
      const __half2* p = reinterpret_cast<const __half2*>(&v[j]);
#pragma unroll
      for (int k = 0; k < 4; ++k)
        acc[j & 1][k] = __hadd2(acc[j & 1][k], p[k]);
    }
  };
  auto CLG = [&](int q) { return (q < GCAP) ? q : GCAP - 1; };

  int4 id0 = *(const int4*)(sp + 4 * g);
  int4 id1 = *(const int4*)(sp + 4 * CLG(g + 1));
  int4 idP = *(const int4*)(sp + 4 * CLG(g + 2));
  int4 idQ = *(const int4*)(sp + 4 * CLG(g + 3));
  int4 idR;
  int nuA = ugp[g + 1];
  int nuB = ugp[CLG(g + 1) + 1];
  int nuC = ugp[CLG(g + 2) + 1];

  float4 va[4], vb[4], vc[4];
  loadRows(va, id0);
  loadRows(vb, id1);

  for (;;) {
    PHASE(va, vc, idP, idR, nuA)
    PHASE(vb, va, idQ, idP, nuB)
    PHASE(vc, vb, idR, idQ, nuC)
  }
}

// Head for one batch half: resolve final version per root via wmask.
__global__ __launch_bounds__(64) void head_a(
    const float4* __restrict__ h4, const float* __restrict__ W_head,
    const float* __restrict__ b_head, const int* __restrict__ root_ids,
    const int* __restrict__ wmask, const int* __restrict__ posarr,
    const int* __restrict__ lw0, int half, float* __restrict__ out) {
  int bl = blockIdx.x;
  int r = threadIdx.x;
  int node = root_ids[r];
  int m = wmask[node];
  int phys;
  if (m) {
    int lj = 31 - __clz(m);
    phys = DST0 + lj * U_ + posarr[lj * N_ + node];
  } else {
    phys = lw0[node];
  }
  float4 p0 = h4[(size_t)phys * FH + bl * 2];
  float4 p1 = h4[(size_t)phys * FH + bl * 2 + 1];
  float v[16];
  const __half2* ph0 = reinterpret_cast<const __half2*>(&p0);
  const __half2* ph1 = reinterpret_cast<const __half2*>(&p1);
#pragma unroll
  for (int k = 0; k < 4; ++k) {
    float2 f0 = __half22float2(ph0[k]);
    float2 f1 = __half22float2(ph1[k]);
    v[2 * k] = f0.x; v[2 * k + 1] = f0.y;
    v[8 + 2 * k] = f1.x; v[8 + 2 * k + 1] = f1.y;
  }
  float acc0 = 0.f, acc1 = 0.f;
#pragma unroll
  for (int d = 0; d < 16; ++d) {
    acc0 = fmaf(v[d], W_head[r * 16 + d], acc0);
    acc1 = fmaf(v[d], W_head[1024 + r * 16 + d], acc1);
  }
  for (int off = 32; off; off >>= 1) {
    acc0 += __shfl_down(acc0, off, 64);
    acc1 += __shfl_down(acc1, off, 64);
  }
  if (r == 0) {
    int gb = half * HBC + bl;
    out[gb * 2 + 0] = acc0 + b_head[0];
    out[gb * 2 + 1] = acc1 + b_head[1];
  }
}

// ---------------- Classic fallback (round-5 proven, 2 KB rows) --------------

__global__ __launch_bounds__(256) void gene_c(
    const float* __restrict__ X, const float* __restrict__ w_in,
    const float* __restrict__ b_in, const int* __restrict__ gene_map,
    float4* __restrict__ h4) {
  int t = blockIdx.x * 256 + threadIdx.x;
  if (t >= G_ * BC) return;
  int b = t % BC;
  int g = t / BC;
  float x = X[b * G_ + g];
  int node = gene_map[g];
  float4 out[2];
  __half2* oh = reinterpret_cast<__half2*>(out);
#pragma unroll
  for (int k = 0; k < 8; ++k) {
    float r0 = fmaf(x, w_in[2 * k], b_in[2 * k]);
    float r1 = fmaf(x, w_in[2 * k + 1], b_in[2 * k + 1]);
    oh[k] = __float22half2_rn(make_float2(r0, r1));
  }
  h4[(size_t)node * F + b * 2] = out[0];
  h4[(size_t)node * F + b * 2 + 1] = out[1];
}

__global__ __launch_bounds__(256, 2) void gather_c(
    const float4* __restrict__ h4, const int* __restrict__ ug,
    const int* __restrict__ ssrc, float4* __restrict__ agg4, int li) {
  int tid = threadIdx.x;
  int lane = tid & 63;
  int wv = __builtin_amdgcn_readfirstlane(blockIdx.x * 4 + (tid >> 6));
  const int* ugp = ug + (size_t)li * EPLG_;
  const int* sp = ssrc + (size_t)li * EPL_;

  int g0 = wv * GPW, gend = g0 + GPW;
  int prevU = (g0 == 0) ? -2 : ugp[g0 - 1];
  int g = g0;
  while (g < gend && ugp[g] == prevU) ++g;
  if (g >= gend) return;
  int curU = ugp[g];
  if (curU < 0) return;
  int uend = ugp[gend - 1];
  int gstop;
  if (uend < 0) {
    gstop = g;
    while (ugp[gstop] >= 0) ++gstop;
  } else {
    gstop = gend;
    while (ugp[gstop] == uend) ++gstop;
  }

  __half2 acc[2][2][4];
  const __half2 z = __half2half2(__float2half(0.f));
#pragma unroll
  for (int j = 0; j < 2; ++j)
#pragma unroll
    for (int r = 0; r < 2; ++r)
#pragma unroll
      for (int k = 0; k < 4; ++k) acc[j][r][k] = z;

  auto flushu = [&](int u) {
#pragma unroll
    for (int r = 0; r < 2; ++r) {
      float4 outv;
      __half2* ov = reinterpret_cast<__half2*>(&outv);
#pragma unroll
      for (int k = 0; k < 4; ++k) {
        float2 f0 = __half22float2(acc[0][r][k]);
        float2 f1 = __half22float2(acc[1][r][k]);
        ov[k] = __float22half2_rn(make_float2(f0.x + f1.x, f0.y + f1.y));
      }
      agg4[(size_t)u * F + lane + r * 64] = outv;
    }
#pragma unroll
    for (int j = 0; j < 2; ++j)
#pragma unroll
      for (int r = 0; r < 2; ++r)
#pragma unroll
        for (int k = 0; k < 4; ++k) acc[j][r][k] = z;
  };
  auto loadRows = [&](float4 (&v)[4][2], int4 id) {
    v[0][0] = h4[(size_t)id.x * F + lane]; v[0][1] = h4[(size_t)id.x * F + lane + 64];
    v[1][0] = h4[(size_t)id.y * F + lane]; v[1][1] = h4[(size_t)id.y * F + lane + 64];
    v[2][0] = h4[(size_t)id.z * F + lane]; v[2][1] = h4[(size_t)id.z * F + lane + 64];
    v[3][0] = h4[(size_t)id.w * F + lane]; v[3][1] = h4[(size_t)id.w * F + lane + 64];
  };
  auto accum = [&](const float4 (&v)[4][2]) {
#pragma unroll
    for (int j = 0; j < 4; ++j)
#pragma unroll
      for (int r = 0; r < 2; ++r) {
        const __half2* p = reinterpret_cast<const __half2*>(&v[j][r]);
#pragma unroll
        for (int k = 0; k < 4; ++k)
          acc[j & 1][r][k] = __hadd2(acc[j & 1][r][k], p[k]);
      }
  };
  auto CLG = [&](int q) { return (q < GCAP) ? q : GCAP - 1; };

  int4 id0 = *(const int4*)(sp + 4 * g);
  int4 id1 = *(const int4*)(sp + 4 * CLG(g + 1));
  int4 idP = *(const int4*)(sp + 4 * CLG(g + 2));
  int4 idQ = *(const int4*)(sp + 4 * CLG(g + 3));
  int4 idR;
  int nuA = ugp[g + 1];
  int nuB = ugp[CLG(g + 1) + 1];
  int nuC = ugp[CLG(g + 2) + 1];

  float4 va[4][2], vb[4][2], vc[4][2];
  loadRows(va, id0);
  loadRows(vb, id1);

  for (;;) {
    PHASE(va, vc, idP, idR, nuA)
    PHASE(vb, va, idQ, idP, nuB)
    PHASE(vc, vb, idR, idQ, nuC)
  }
}
#undef PHASE

__global__ __launch_bounds__(256) void dense_c(
    const float4* __restrict__ agg4, const float* __restrict__ W,
    const float* __restrict__ bias, const int* __restrict__ dst_unique,
    float4* __restrict__ h4, int li) {
  __shared__ float Wlds[256];
  int tid = threadIdx.x;
  Wlds[tid] = W[li * 256 + tid];
  __syncthreads();
  int u = __builtin_amdgcn_readfirstlane(blockIdx.x * 4 + (tid >> 6));
  int b = tid & 63;
  float4 c0 = agg4[(size_t)u * F + b * 2];
  float4 c1 = agg4[(size_t)u * F + b * 2 + 1];
  float a[16];
  {
    const __half2* p0 = reinterpret_cast<const __half2*>(&c0);
    const __half2* p1 = reinterpret_cast<const __half2*>(&c1);
#pragma unroll
    for (int k = 0; k < 4; ++k) {
      float2 f0 = __half22float2(p0[k]);
      float2 f1 = __half22float2(p1[k]);
      a[2 * k] = f0.x; a[2 * k + 1] = f0.y;
      a[8 + 2 * k] = f1.x; a[8 + 2 * k + 1] = f1.y;
    }
  }
  float m[16];
#pragma unroll
  for (int j = 0; j < 16; ++j) m[j] = 0.f;
#pragma unroll
  for (int d = 0; d < 16; ++d) {
    float s = a[d];
    const float4* wr = (const float4*)&Wlds[d * 16];
    float4 w0 = wr[0], w1 = wr[1], w2 = wr[2], w3 = wr[3];
    m[0] = fmaf(s, w0.x, m[0]);  m[1] = fmaf(s, w0.y, m[1]);
    m[2] = fmaf(s, w0.z, m[2]);  m[3] = fmaf(s, w0.w, m[3]);
    m[4] = fmaf(s, w1.x, m[4]);  m[5] = fmaf(s, w1.y, m[5]);
    m[6] = fmaf(s, w1.z, m[6]);  m[7] = fmaf(s, w1.w, m[7]);
    m[8] = fmaf(s, w2.x, m[8]);  m[9] = fmaf(s, w2.y, m[9]);
    m[10] = fmaf(s, w2.z, m[10]); m[11] = fmaf(s, w2.w, m[11]);
    m[12] = fmaf(s, w3.x, m[12]); m[13] = fmaf(s, w3.y, m[13]);
    m[14] = fmaf(s, w3.z, m[14]); m[15] = fmaf(s, w3.w, m[15]);
  }
  int node = dst_unique[li * U_ + u];
  const float4* bp = (const float4*)(bias + (size_t)node * 16);
  float4 b0 = bp[0], b1 = bp[1], b2 = bp[2], b3 = bp[3];
  float bb[16] = {b0.x, b0.y, b0.z, b0.w, b1.x, b1.y, b1.z, b1.w,
                  b2.x, b2.y, b2.z, b2.w, b3.x, b3.y, b3.z, b3.w};
  float4 o0, o1;
  __half2* ov0 = reinterpret_cast<__half2*>(&o0);
  __half2* ov1 = reinterpret_cast<__half2*>(&o1);
#pragma unroll
  for (int k = 0; k < 4; ++k) {
    ov0[k] = __float22half2_rn(make_float2(tanh_fast(m[2 * k] + bb[2 * k]),
                                           tanh_fast(m[2 * k + 1] + bb[2 * k + 1])));
    ov1[k] = __float22half2_rn(make_float2(tanh_fast(m[8 + 2 * k] + bb[8 + 2 * k]),
                                           tanh_fast(m[8 + 2 * k + 1] + bb[8 + 2 * k + 1])));
  }
  h4[(size_t)node * F + b * 2] = o0;
  h4[(size_t)node * F + b * 2 + 1] = o1;
}

__global__ __launch_bounds__(64) void head_c(
    const float4* __restrict__ h4, const float* __restrict__ W_head,
    const float* __restrict__ b_head, const int* __restrict__ root_ids,
    float* __restrict__ out) {
  int bl = blockIdx.x;
  int r = threadIdx.x;
  int node = root_ids[r];
  float4 p0 = h4[(size_t)node * F + bl * 2];
  float4 p1 = h4[(size_t)node * F + bl * 2 + 1];
  float v[16];
  const __half2* ph0 = reinterpret_cast<const __half2*>(&p0);
  const __half2* ph1 = reinterpret_cast<const __half2*>(&p1);
#pragma unroll
  for (int k = 0; k < 4; ++k) {
    float2 f0 = __half22float2(ph0[k]);
    float2 f1 = __half22float2(ph1[k]);
    v[2 * k] = f0.x; v[2 * k + 1] = f0.y;
    v[8 + 2 * k] = f1.x; v[8 + 2 * k + 1] = f1.y;
  }
  float acc0 = 0.f, acc1 = 0.f;
#pragma unroll
  for (int d = 0; d < 16; ++d) {
    acc0 = fmaf(v[d], W_head[r * 16 + d], acc0);
    acc1 = fmaf(v[d], W_head[1024 + r * 16 + d], acc1);
  }
  for (int off = 32; off; off >>= 1) {
    acc0 += __shfl_down(acc0, off, 64);
    acc1 += __shfl_down(acc1, off, 64);
  }
  if (r == 0) {
    out[bl * 2 + 0] = acc0 + b_head[0];
    out[bl * 2 + 1] = acc1 + b_head[1];
  }
}

__global__ void zero_out_k(float* out, int n) {
  int t = blockIdx.x * 256 + threadIdx.x;
  if (t < n) out[t] = 0.f;
}

// ---------------- Host side ----------------

static size_t arena_bytes() {
  return (size_t)AROWS * FH * 16 +
         (size_t)L_ * U_ * 4 +            // cnt
         (size_t)2 * (N_ + 1) * 4 +       // wmask + lw0 (contiguous)
         (size_t)L_ * (U_ + 1) * 4 +      // offs
         (size_t)L_ * E_ * 4 +            // rank
         (size_t)L_ * NB * U_ * 4 +       // part (counts -> block bases)
         (size_t)L_ * EPL_ * 4 +          // ssrc
         (size_t)L_ * EPLG_ * 4 +         // ug
         (size_t)L_ * N_ * 4;             // posarr
}
static size_t classic_bytes() {
  return (size_t)(N_ + 1) * F * 16 + (size_t)U_ * F * 16 +
         (size_t)L_ * U_ * 4 + (size_t)L_ * (U_ + 1) * 4 +
         (size_t)L_ * E_ * 4 + (size_t)L_ * NB * U_ * 4 +
         (size_t)L_ * EPL_ * 4 + (size_t)L_ * EPLG_ * 4;
}

extern "C" void kernel_launch(void* const* d_in, const int* in_sizes, int n_in,
                              void* d_out, int out_size, void* d_ws, size_t ws_size,
                              hipStream_t stream) {
  const float* X = (const float*)d_in[0];
  const float* w_in = (const float*)d_in[1];
  const float* b_in = (const float*)d_in[2];
  const float* W = (const float*)d_in[3];
  const float* bias = (const float*)d_in[4];
  const float* W_head = (const float*)d_in[5];
  const float* b_head = (const float*)d_in[6];
  const int* gene_map = (const int*)d_in[7];
  const int* src = (const int*)d_in[8];
  const int* dst_pos = (const int*)d_in[9];
  const int* dst_unique = (const int*)d_in[10];
  const int* root_ids = (const int*)d_in[11];
  float* out = (float*)d_out;

  dim3 hgrid(NB, L_);
  dim3 spgrid((U_ + 255) / 256, L_);
  dim3 scgrid((E_ / 4 + 255) / 256, L_);
  const int pf_grid = (L_ * U_ + L_ * 1024 + 255) / 256;
  const int gather_grid = (SW + 3) / 4;

  if (ws_size >= arena_bytes()) {
    // ---------- Arena path: fused gather+dense, two batch halves ----------
    char* ws = (char*)d_ws;
    float4* arena = (float4*)ws;
    size_t off = (size_t)AROWS * FH * 16;
    int* cnt = (int*)(ws + off);    off += (size_t)L_ * U_ * 4;
    int* wmask = (int*)(ws + off);  off += (size_t)(N_ + 1) * 4;
    int* lw0 = (int*)(ws + off);    off += (size_t)(N_ + 1) * 4;
    int* offs = (int*)(ws + off);   off += (size_t)L_ * (U_ + 1) * 4;
    int* rank = (int*)(ws + off);   off += (size_t)L_ * E_ * 4;
    int* part = (int*)(ws + off);   off += (size_t)L_ * NB * U_ * 4;
    int* ssrc = (int*)(ws + off);   off += (size_t)L_ * EPL_ * 4;
    int* ug = (int*)(ws + off);     off += (size_t)L_ * EPLG_ * 4;
    int* posarr = (int*)(ws + off);

    hipMemsetAsync(wmask, 0, (size_t)2 * (N_ + 1) * 4, stream);
    hist_lds_k<<<hgrid, 256, 0, stream>>>(dst_pos, rank, part);
    sumpart_k<<<spgrid, 256, 0, stream>>>(part, cnt);
    scan_kernel<<<L_, 1024, 0, stream>>>(cnt, offs);
    scatter_kernel<<<scgrid, 256, 0, stream>>>(dst_pos, src, offs, part, rank,
                                               ssrc);
    pad_fill_ug_k<<<pf_grid, 256, 0, stream>>>(cnt, offs, ssrc, ug, arena);
    mark_k<<<(L_ * U_ + G_ + 255) / 256, 256, 0, stream>>>(dst_unique, gene_map,
                                                           wmask, posarr, lw0);
    dim3 rgrid((EPL_ + 255) / 256, L_);
    remap_k<<<rgrid, 256, 0, stream>>>(offs, wmask, posarr, lw0, ssrc);

    for (int half = 0; half < 2; ++half) {
      gene_a<<<G_ / 8, 256, 0, stream>>>(X, w_in, b_in, arena, half);
      for (int li = 0; li < L_; ++li) {
        gfused_a<<<gather_grid, 256, 0, stream>>>(arena, ug, ssrc, W, bias,
                                                  dst_unique, arena, li);
      }
      head_a<<<HBC, 64, 0, stream>>>(arena, W_head, b_head, root_ids, wmask,
                                     posarr, lw0, half, out);
    }
  } else if (ws_size >= classic_bytes()) {
    // ---------- Classic path (round-5 proven structure) ----------
    const size_t h_bytes = (size_t)(N_ + 1) * F * 16;
    const size_t agg_bytes = (size_t)U_ * F * 16;
    char* ws = (char*)d_ws;
    float4* h4 = (float4*)ws;
    float4* agg4 = (float4*)(ws + h_bytes);
    size_t off = h_bytes + agg_bytes;
    int* cnt = (int*)(ws + off);   off += (size_t)L_ * U_ * 4;
    int* offs = (int*)(ws + off);  off += (size_t)L_ * (U_ + 1) * 4;
    int* rank = (int*)(ws + off);  off += (size_t)L_ * E_ * 4;
    int* part = (int*)(ws + off);  off += (size_t)L_ * NB * U_ * 4;
    int* ssrc = (int*)(ws + off);  off += (size_t)L_ * EPL_ * 4;
    int* ug = (int*)(ws + off);

    hipMemsetAsync(h4, 0, h_bytes, stream);
    hist_lds_k<<<hgrid, 256, 0, stream>>>(dst_pos, rank, part);
    sumpart_k<<<spgrid, 256, 0, stream>>>(part, cnt);
    scan_kernel<<<L_, 1024, 0, stream>>>(cnt, offs);
    scatter_kernel<<<scgrid, 256, 0, stream>>>(dst_pos, src, offs, part, rank,
                                               ssrc);
    pad_fill_ug_k<<<pf_grid, 256, 0, stream>>>(cnt, offs, ssrc, ug, nullptr);
    gene_c<<<(G_ * BC + 255) / 256, 256, 0, stream>>>(X, w_in, b_in, gene_map, h4);
    const int dense_grid = U_ * BC / 256;
    for (int li = 0; li < L_; ++li) {
      gather_c<<<gather_grid, 256, 0, stream>>>(h4, ug, ssrc, agg4, li);
      dense_c<<<dense_grid, 256, 0, stream>>>(agg4, W, bias, dst_unique, h4, li);
    }
    head_c<<<BC, 64, 0, stream>>>(h4, W_head, b_head, root_ids, out);
  } else {
    zero_out_k<<<(out_size + 255) / 256, 256, 0, stream>>>(out, out_size);
  }
}